// Round 2
// baseline (29191.837 us; speedup 1.0000x reference)
//
#include <hip/hip_runtime.h>
#include <cmath>

#define HH 48
#define WW 48
#define HWSZ 2304
#define BB 8
#define TT 32

// Fused ConvLSTM step. One block = (8-row tile) x (4 hidden channels) x batch.
// 192 threads = 48 cols x 4; each thread owns 2 rows x 1 col x 4 hidden ch.
// Weights are read via wave-uniform (scalar) loads straight from global;
// only the input tile goes through LDS, amortized over the 4 hidden channels.
template<int CIN, int CHID>
__global__ __launch_bounds__(192) void convlstm_step(
    const float* __restrict__ xin, long xbstride,   // x-part, per-batch stride
    const float* __restrict__ hin,                  // [B][CHID][HW] h_prev
    const float* __restrict__ w,                    // [4*CHID][CIN+CHID][3][3]
    const float* __restrict__ bias,                 // [4*CHID]
    float* __restrict__ cstate,                     // [B][CHID][HW], in-place
    float* __restrict__ hout,                       // [B][CHID][HW]
    float* __restrict__ seq_t)                      // if !=null and b==0: [CHID][HW]
{
    constexpr int CTOT  = CIN + CHID;
    constexpr int NOC   = 4;    // hidden channels per block
    constexpr int ROWS  = 8;    // output rows per block
    constexpr int CHUNK = 4;    // input channels staged per iteration

    __shared__ float tile[CHUNK][ROWS + 2][50];   // halo rows/cols, zero-padded

    const int tx  = threadIdx.x;        // 0..47
    const int ty  = threadIdx.y;        // 0..3
    const int tid = ty * 48 + tx;       // 0..191
    const int ty0 = blockIdx.x * ROWS;  // tile row base
    const int hc0 = blockIdx.y * NOC;   // hidden-channel base
    const int b   = blockIdx.z;         // batch

    float acc[NOC][4][2];   // [hidden ch][gate][pixel-row]
    #pragma unroll
    for (int h = 0; h < NOC; ++h)
        #pragma unroll
        for (int g = 0; g < 4; ++g) { acc[h][g][0] = 0.f; acc[h][g][1] = 0.f; }

    const float* xb = xin + (long)b * xbstride;
    const float* hb = hin + (long)b * CHID * HWSZ;

    for (int ic0 = 0; ic0 < CTOT; ic0 += CHUNK) {
        __syncthreads();
        // Stage CHUNK input channels with halo (zero padding outside image).
        constexpr int NSTG = CHUNK * (ROWS + 2) * 50;
        for (int idx = tid; idx < NSTG; idx += 192) {
            int chi = idx / ((ROWS + 2) * 50);
            int rem = idx - chi * ((ROWS + 2) * 50);
            int row = rem / 50;
            int col = rem - row * 50;
            int gy = ty0 - 1 + row;
            int gx = col - 1;
            int ic = ic0 + chi;
            float v = 0.f;
            if (ic < CTOT && gy >= 0 && gy < HH && gx >= 0 && gx < WW) {
                v = (ic < CIN) ? xb[ic * HWSZ + gy * WW + gx]
                               : hb[(ic - CIN) * HWSZ + gy * WW + gx];
            }
            tile[chi][row][col] = v;
        }
        __syncthreads();

        #pragma unroll
        for (int chi = 0; chi < CHUNK; ++chi) {
            const int ic = ic0 + chi;
            if (ic < CTOT) {
                // 4 input rows x 3 cols cover this thread's 2 output rows.
                float vin[4][3];
                #pragma unroll
                for (int rr = 0; rr < 4; ++rr)
                    #pragma unroll
                    for (int cc = 0; cc < 3; ++cc)
                        vin[rr][cc] = tile[chi][ty * 2 + rr][tx + cc];

                #pragma unroll
                for (int g = 0; g < 4; ++g) {
                    #pragma unroll
                    for (int h = 0; h < NOC; ++h) {
                        // Block-uniform index -> scalar (s_load) weight reads.
                        const float* wp =
                            w + (((long)(g * CHID + hc0 + h)) * CTOT + ic) * 9;
                        float wv[9];
                        #pragma unroll
                        for (int k = 0; k < 9; ++k) wv[k] = wp[k];
                        #pragma unroll
                        for (int px = 0; px < 2; ++px)
                            #pragma unroll
                            for (int dy = 0; dy < 3; ++dy)
                                #pragma unroll
                                for (int dx = 0; dx < 3; ++dx)
                                    acc[h][g][px] +=
                                        vin[px + dy][dx] * wv[dy * 3 + dx];
                    }
                }
            }
        }
    }

    // LSTM pointwise update (gate order: i, f, o, g).
    #pragma unroll
    for (int h = 0; h < NOC; ++h) {
        const int c = hc0 + h;
        const float bi = bias[c];
        const float bf = bias[CHID + c];
        const float bo = bias[2 * CHID + c];
        const float bg = bias[3 * CHID + c];
        #pragma unroll
        for (int px = 0; px < 2; ++px) {
            int y = ty0 + ty * 2 + px;
            long off = ((long)(b * CHID + c)) * HWSZ + y * WW + tx;
            float i_ = 1.f / (1.f + __expf(-(acc[h][0][px] + bi)));
            float f_ = 1.f / (1.f + __expf(-(acc[h][1][px] + bf)));
            float o_ = 1.f / (1.f + __expf(-(acc[h][2][px] + bo)));
            float g_ = tanhf(acc[h][3][px] + bg);
            float cp = cstate[off];
            float cn = f_ * cp + i_ * g_;
            float hn = o_ * tanhf(cn);
            cstate[off] = cn;
            hout[off] = hn;
            if (seq_t != nullptr && b == 0)
                seq_t[c * HWSZ + y * WW + tx] = hn;
        }
    }
}

// out[k] = bl + sum_j wl[j] * seq_flat[32k + j]
__global__ void head_kernel(const float* __restrict__ seq,
                            const float* __restrict__ wl,
                            const float* __restrict__ bl,
                            float* __restrict__ out, int n)
{
    __shared__ float wls[32];
    if (threadIdx.x < 32) wls[threadIdx.x] = wl[threadIdx.x];
    __syncthreads();
    int k = blockIdx.x * 256 + threadIdx.x;
    if (k >= n) return;
    const float4* p = (const float4*)(seq + (long)k * 32);
    float s = bl[0];
    #pragma unroll
    for (int q = 0; q < 8; ++q) {
        float4 f = p[q];
        s += f.x * wls[q * 4 + 0] + f.y * wls[q * 4 + 1]
           + f.z * wls[q * 4 + 2] + f.w * wls[q * 4 + 3];
    }
    out[k] = s;
}

extern "C" void kernel_launch(void* const* d_in, const int* in_sizes, int n_in,
                              void* d_out, int out_size, void* d_ws, size_t ws_size,
                              hipStream_t stream)
{
    const float* x  = (const float*)d_in[0];   // [8,32,1,48,48]
    const float* w0 = (const float*)d_in[1];   // [256,65,3,3]
    const float* b0 = (const float*)d_in[2];   // [256]
    const float* w1 = (const float*)d_in[3];   // [128,96,3,3]
    const float* b1 = (const float*)d_in[4];   // [128]
    const float* wl = (const float*)d_in[5];   // [1,32]
    const float* bl = (const float*)d_in[6];   // [1]
    float* out = (float*)d_out;                // [73728]

    float* ws = (float*)d_ws;
    const long n0 = 8L * 64 * HWSZ;   // 1179648
    const long n1 = 8L * 32 * HWSZ;   // 589824
    float* h0a = ws; ws += n0;
    float* h0b = ws; ws += n0;
    float* c0  = ws; ws += n0;
    float* h1a = ws; ws += n1;
    float* h1b = ws; ws += n1;
    float* c1  = ws; ws += n1;
    float* seq = ws; ws += 32L * 32 * HWSZ;    // [T][32][2304] for batch 0

    // Zero initial states every call (deterministic; ws is not re-poisoned).
    hipMemsetAsync(h0a, 0, n0 * 4, stream);
    hipMemsetAsync(c0,  0, n0 * 4, stream);
    hipMemsetAsync(h1a, 0, n1 * 4, stream);
    hipMemsetAsync(c1,  0, n1 * 4, stream);

    float* h0c = h0a; float* h0n = h0b;
    float* h1c = h1a; float* h1n = h1b;
    for (int t = 0; t < TT; ++t) {
        convlstm_step<1, 64><<<dim3(6, 16, BB), dim3(48, 4), 0, stream>>>(
            x + (long)t * HWSZ, (long)TT * HWSZ, h0c, w0, b0, c0, h0n, nullptr);
        convlstm_step<64, 32><<<dim3(6, 8, BB), dim3(48, 4), 0, stream>>>(
            h0n, (long)64 * HWSZ, h1c, w1, b1, c1, h1n,
            seq + (long)t * 32 * HWSZ);
        float* tmp;
        tmp = h0c; h0c = h0n; h0n = tmp;
        tmp = h1c; h1c = h1n; h1n = tmp;
    }
    head_kernel<<<(73728 + 255) / 256, 256, 0, stream>>>(seq, wl, bl, out, 73728);
}

// Round 3
// 15500.439 us; speedup vs baseline: 1.8833x; 1.8833x over previous
//
#include <hip/hip_runtime.h>
#include <cmath>

#define HH 48
#define WW 48
#define HWSZ 2304
#define BB 8
#define TT 32

// Fused ConvLSTM step. One block = (8-row tile) x (NOC hidden channels) x batch.
// 192 threads = 48 cols x 4 ty; each thread owns 2 output rows x 1 col x NOC ch.
// Per chunk: stage CHUNK input channels (with halo) + their weights into LDS,
// then accumulate. Weights packed [chi][h][k][4 gates] so one float4 broadcast
// feeds 8 FMAs (4 gates x 2 pixel rows).
template<int CIN, int CHID, int NOC, int CHUNK>
__global__ __launch_bounds__(192) void convlstm_step(
    const float* __restrict__ xin, long xbstride,   // x-part, per-batch stride
    const float* __restrict__ hin,                  // [B][CHID][HW] h_prev
    const float* __restrict__ w,                    // [4*CHID][CIN+CHID][3][3]
    const float* __restrict__ bias,                 // [4*CHID]
    float* __restrict__ cstate,                     // [B][CHID][HW], in-place
    float* __restrict__ hout,                       // [B][CHID][HW]
    float* __restrict__ seq_t)                      // if !=null and b==0: [CHID][HW]
{
    constexpr int CTOT   = CIN + CHID;
    constexpr int NCHUNK = (CTOT + CHUNK - 1) / CHUNK;

    __shared__ float tile[CHUNK][10][50];        // 8 rows + halo, 48 cols + halo
    __shared__ float wlds[CHUNK][NOC][9][4];     // [chi][h][tap][gate]

    const int tx  = threadIdx.x;        // 0..47
    const int ty  = threadIdx.y;        // 0..3
    const int tid = ty * 48 + tx;       // 0..191
    const int ty0 = blockIdx.x * 8;     // tile row base
    const int hc0 = blockIdx.y * NOC;   // hidden-channel base
    const int b   = blockIdx.z;         // batch

    float acc[NOC][4][2];   // [hidden ch][gate][pixel-row]
    #pragma unroll
    for (int h = 0; h < NOC; ++h)
        #pragma unroll
        for (int g = 0; g < 4; ++g) { acc[h][g][0] = 0.f; acc[h][g][1] = 0.f; }

    const float* xb = xin + (long)b * xbstride;
    const float* hb = hin + (long)b * CHID * HWSZ;

    for (int chunk = 0; chunk < NCHUNK; ++chunk) {
        const int ic0 = chunk * CHUNK;
        __syncthreads();
        // Stage CHUNK input channels with halo (zero padding outside image).
        for (int idx = tid; idx < CHUNK * 500; idx += 192) {
            int chi = idx / 500;
            int rem = idx - chi * 500;
            int row = rem / 50;
            int col = rem - row * 50;
            int gy = ty0 - 1 + row;
            int gx = col - 1;
            int ic = ic0 + chi;
            float v = 0.f;
            if (ic < CTOT && gy >= 0 && gy < HH && gx >= 0 && gx < WW) {
                v = (ic < CIN) ? xb[ic * HWSZ + gy * WW + gx]
                               : hb[(ic - CIN) * HWSZ + gy * WW + gx];
            }
            tile[chi][row][col] = v;
        }
        // Stage weights for this chunk: [chi][h][k][g], linear idx = write addr.
        for (int idx = tid; idx < CHUNK * NOC * 36; idx += 192) {
            int g = idx & 3;
            int t = idx >> 2;
            int k = t % 9; t /= 9;
            int h = t % NOC;
            int chi = t / NOC;
            int ic = ic0 + chi;
            float v = 0.f;
            if (ic < CTOT)
                v = w[(((long)(g * CHID + hc0 + h)) * CTOT + ic) * 9 + k];
            ((float*)wlds)[idx] = v;
        }
        __syncthreads();

        #pragma unroll 1
        for (int chi = 0; chi < CHUNK; ++chi) {
            // 4 input rows x 3 cols cover this thread's 2 output rows.
            float vin[4][3];
            #pragma unroll
            for (int rr = 0; rr < 4; ++rr)
                #pragma unroll
                for (int cc = 0; cc < 3; ++cc)
                    vin[rr][cc] = tile[chi][ty * 2 + rr][tx + cc];

            #pragma unroll
            for (int h = 0; h < NOC; ++h) {
                const float4* wp = (const float4*)&wlds[chi][h][0][0];
                #pragma unroll
                for (int k = 0; k < 9; ++k) {
                    float4 wv = wp[k];     // {wi, wf, wo, wg} for tap k
                    const int dy = k / 3, dx = k % 3;
                    acc[h][0][0] += vin[dy][dx]     * wv.x;
                    acc[h][1][0] += vin[dy][dx]     * wv.y;
                    acc[h][2][0] += vin[dy][dx]     * wv.z;
                    acc[h][3][0] += vin[dy][dx]     * wv.w;
                    acc[h][0][1] += vin[dy + 1][dx] * wv.x;
                    acc[h][1][1] += vin[dy + 1][dx] * wv.y;
                    acc[h][2][1] += vin[dy + 1][dx] * wv.z;
                    acc[h][3][1] += vin[dy + 1][dx] * wv.w;
                }
            }
        }
    }

    // LSTM pointwise update (gate order: i, f, o, g).
    #pragma unroll
    for (int h = 0; h < NOC; ++h) {
        const int c = hc0 + h;
        const float bi = bias[c];
        const float bf = bias[CHID + c];
        const float bo = bias[2 * CHID + c];
        const float bg = bias[3 * CHID + c];
        #pragma unroll
        for (int px = 0; px < 2; ++px) {
            int y = ty0 + ty * 2 + px;
            long off = ((long)(b * CHID + c)) * HWSZ + y * WW + tx;
            float i_ = 1.f / (1.f + __expf(-(acc[h][0][px] + bi)));
            float f_ = 1.f / (1.f + __expf(-(acc[h][1][px] + bf)));
            float o_ = 1.f / (1.f + __expf(-(acc[h][2][px] + bo)));
            float g_ = tanhf(acc[h][3][px] + bg);
            float cp = cstate[off];
            float cn = f_ * cp + i_ * g_;
            float hn = o_ * tanhf(cn);
            cstate[off] = cn;
            hout[off] = hn;
            if (seq_t != nullptr && b == 0)
                seq_t[c * HWSZ + y * WW + tx] = hn;
        }
    }
}

// out[k] = bl + sum_j wl[j] * seq_flat[32k + j]
__global__ void head_kernel(const float* __restrict__ seq,
                            const float* __restrict__ wl,
                            const float* __restrict__ bl,
                            float* __restrict__ out, int n)
{
    __shared__ float wls[32];
    if (threadIdx.x < 32) wls[threadIdx.x] = wl[threadIdx.x];
    __syncthreads();
    int k = blockIdx.x * 256 + threadIdx.x;
    if (k >= n) return;
    const float4* p = (const float4*)(seq + (long)k * 32);
    float s = bl[0];
    #pragma unroll
    for (int q = 0; q < 8; ++q) {
        float4 f = p[q];
        s += f.x * wls[q * 4 + 0] + f.y * wls[q * 4 + 1]
           + f.z * wls[q * 4 + 2] + f.w * wls[q * 4 + 3];
    }
    out[k] = s;
}

extern "C" void kernel_launch(void* const* d_in, const int* in_sizes, int n_in,
                              void* d_out, int out_size, void* d_ws, size_t ws_size,
                              hipStream_t stream)
{
    const float* x  = (const float*)d_in[0];   // [8,32,1,48,48]
    const float* w0 = (const float*)d_in[1];   // [256,65,3,3]
    const float* b0 = (const float*)d_in[2];   // [256]
    const float* w1 = (const float*)d_in[3];   // [128,96,3,3]
    const float* b1 = (const float*)d_in[4];   // [128]
    const float* wl = (const float*)d_in[5];   // [1,32]
    const float* bl = (const float*)d_in[6];   // [1]
    float* out = (float*)d_out;                // [73728]

    float* ws = (float*)d_ws;
    const long n0 = 8L * 64 * HWSZ;   // 1179648
    const long n1 = 8L * 32 * HWSZ;   // 589824
    float* h0a = ws; ws += n0;
    float* h0b = ws; ws += n0;
    float* c0  = ws; ws += n0;
    float* h1a = ws; ws += n1;
    float* h1b = ws; ws += n1;
    float* c1  = ws; ws += n1;
    float* seq = ws; ws += 32L * 32 * HWSZ;    // [T][32][2304] for batch 0

    // Zero initial states every call (deterministic; ws is not re-poisoned).
    hipMemsetAsync(h0a, 0, n0 * 4, stream);
    hipMemsetAsync(c0,  0, n0 * 4, stream);
    hipMemsetAsync(h1a, 0, n1 * 4, stream);
    hipMemsetAsync(c1,  0, n1 * 4, stream);

    float* h0c = h0a; float* h0n = h0b;
    float* h1c = h1a; float* h1n = h1b;
    for (int t = 0; t < TT; ++t) {
        // layer0: 65 in-ch, 5 chunks of 13; 16 oc-groups of 4 -> 768 blocks
        convlstm_step<1, 64, 4, 13><<<dim3(6, 16, BB), dim3(48, 4), 0, stream>>>(
            x + (long)t * HWSZ, (long)TT * HWSZ, h0c, w0, b0, c0, h0n, nullptr);
        // layer1: 96 in-ch, 8 chunks of 12; 16 oc-groups of 2 -> 768 blocks
        convlstm_step<64, 32, 2, 12><<<dim3(6, 16, BB), dim3(48, 4), 0, stream>>>(
            h0n, (long)64 * HWSZ, h1c, w1, b1, c1, h1n,
            seq + (long)t * 32 * HWSZ);
        float* tmp;
        tmp = h0c; h0c = h0n; h0n = tmp;
        tmp = h1c; h1c = h1n; h1n = tmp;
    }
    head_kernel<<<(73728 + 255) / 256, 256, 0, stream>>>(seq, wl, bl, out, 73728);
}

// Round 4
// 7616.419 us; speedup vs baseline: 3.8328x; 2.0351x over previous
//
#include <hip/hip_runtime.h>
#include <cmath>

#define HH 48
#define WW 48
#define HWSZ 2304
#define BB 8
#define TT 32

// Fused ConvLSTM step. One block = (4-row tile) x (NOC hidden channels) x batch.
// 192 threads = 48 cols x 4 ty. ty maps to (hidden-channel slot, row group):
//   hty = ty % NOC   -> which of the NOC hidden channels this thread computes
//   rb  = (ty/NOC)*NOC -> row base; each thread owns RPT=NOC consecutive rows.
// Per chunk: stage CHUNK input channels (4 rows + halo) + weights into LDS.
// Weights packed [chi][h][tap][gate]; each thread reads only its own h's 9
// float4 taps per input channel (broadcast within ty-group, conflict-free).
template<int CIN, int CHID, int NOC, int CHUNK>
__global__ __launch_bounds__(192, 5) void convlstm_step(
    const float* __restrict__ xin, long xbstride,   // x-part, per-batch stride
    const float* __restrict__ hin,                  // [B][CHID][HW] h_prev
    const float* __restrict__ w,                    // [4*CHID][CIN+CHID][3][3]
    const float* __restrict__ bias,                 // [4*CHID]
    float* __restrict__ cstate,                     // [B][CHID][HW], in-place
    float* __restrict__ hout,                       // [B][CHID][HW]
    float* __restrict__ seq_t)                      // if !=null and b==0: [CHID][HW]
{
    constexpr int CTOT = CIN + CHID;
    static_assert(CTOT % CHUNK == 0, "chunks must tile channels exactly");
    constexpr int NCHUNK = CTOT / CHUNK;
    constexpr int RPT = NOC;                // rows per thread
    static_assert(4 % NOC == 0, "");

    __shared__ float tile[CHUNK][6][50];            // 4 rows + halo, 48 + halo
    __shared__ float wlds[CHUNK][NOC][9][4];        // [chi][h][tap][gate]

    const int tx  = threadIdx.x;        // 0..47
    const int ty  = threadIdx.y;        // 0..3
    const int tid = ty * 48 + tx;
    const int ty0 = blockIdx.x * 4;     // tile row base (12 tiles of 4 rows)
    const int hc0 = blockIdx.y * NOC;   // hidden-channel base
    const int b   = blockIdx.z;         // batch

    const int hty = ty % NOC;           // hidden-channel slot
    const int rb  = (ty / NOC) * RPT;   // row base within tile (0 or 2)

    float acc[4][RPT];                  // [gate][row]
    #pragma unroll
    for (int g = 0; g < 4; ++g)
        #pragma unroll
        for (int r = 0; r < RPT; ++r) acc[g][r] = 0.f;

    const float* xb = xin + (long)b * xbstride;
    const float* hb = hin + (long)b * CHID * HWSZ;

    for (int chunk = 0; chunk < NCHUNK; ++chunk) {
        const int ic0 = chunk * CHUNK;
        __syncthreads();
        // Stage CHUNK input channels, 6 rows x 50 cols each (zero-padded halo).
        for (int idx = tid; idx < CHUNK * 300; idx += 192) {
            int chi = idx / 300;
            int rem = idx - chi * 300;
            int row = rem / 50;
            int col = rem - row * 50;
            int gy = ty0 - 1 + row;
            int gx = col - 1;
            int ic = ic0 + chi;
            float v = 0.f;
            if (gy >= 0 && gy < HH && gx >= 0 && gx < WW)
                v = (ic < CIN) ? xb[ic * HWSZ + gy * WW + gx]
                               : hb[(ic - CIN) * HWSZ + gy * WW + gx];
            tile[chi][row][col] = v;
        }
        // Stage weights: linear idx == LDS write addr, layout [chi][h][k][g].
        for (int idx = tid; idx < CHUNK * NOC * 36; idx += 192) {
            int g = idx & 3;
            int t2 = idx >> 2;
            int k = t2 % 9; t2 /= 9;
            int h = t2 % NOC;
            int chi = t2 / NOC;
            int ic = ic0 + chi;
            ((float*)wlds)[idx] =
                w[(((long)(g * CHID + hc0 + h)) * CTOT + ic) * 9 + k];
        }
        __syncthreads();

        #pragma unroll 1
        for (int chi = 0; chi < CHUNK; ++chi) {
            // RPT+2 input rows x 3 cols cover this thread's RPT output rows.
            float vin[RPT + 2][3];
            #pragma unroll
            for (int rr = 0; rr < RPT + 2; ++rr)
                #pragma unroll
                for (int cc = 0; cc < 3; ++cc)
                    vin[rr][cc] = tile[chi][rb + rr][tx + cc];

            const float4* wp = (const float4*)&wlds[chi][hty][0][0];
            #pragma unroll
            for (int k = 0; k < 9; ++k) {
                float4 wv = wp[k];          // {wi, wf, wo, wg} for tap k
                const int dy = k / 3, dx = k % 3;
                #pragma unroll
                for (int r = 0; r < RPT; ++r) {
                    acc[0][r] += vin[r + dy][dx] * wv.x;
                    acc[1][r] += vin[r + dy][dx] * wv.y;
                    acc[2][r] += vin[r + dy][dx] * wv.z;
                    acc[3][r] += vin[r + dy][dx] * wv.w;
                }
            }
        }
    }

    // LSTM pointwise update (gate order: i, f, o, g).
    {
        const int c = hc0 + hty;
        const float bi = bias[c];
        const float bf_ = bias[CHID + c];
        const float bo = bias[2 * CHID + c];
        const float bg = bias[3 * CHID + c];
        #pragma unroll
        for (int r = 0; r < RPT; ++r) {
            int y = ty0 + rb + r;
            long off = ((long)(b * CHID + c)) * HWSZ + y * WW + tx;
            float i_ = 1.f / (1.f + __expf(-(acc[0][r] + bi)));
            float f_ = 1.f / (1.f + __expf(-(acc[1][r] + bf_)));
            float o_ = 1.f / (1.f + __expf(-(acc[2][r] + bo)));
            float g_ = tanhf(acc[3][r] + bg);
            float cp = cstate[off];
            float cn = f_ * cp + i_ * g_;
            float hn = o_ * tanhf(cn);
            cstate[off] = cn;
            hout[off] = hn;
            if (seq_t != nullptr && b == 0)
                seq_t[c * HWSZ + y * WW + tx] = hn;
        }
    }
}

// out[k] = bl + sum_j wl[j] * seq_flat[32k + j]
__global__ void head_kernel(const float* __restrict__ seq,
                            const float* __restrict__ wl,
                            const float* __restrict__ bl,
                            float* __restrict__ out, int n)
{
    __shared__ float wls[32];
    if (threadIdx.x < 32) wls[threadIdx.x] = wl[threadIdx.x];
    __syncthreads();
    int k = blockIdx.x * 256 + threadIdx.x;
    if (k >= n) return;
    const float4* p = (const float4*)(seq + (long)k * 32);
    float s = bl[0];
    #pragma unroll
    for (int q = 0; q < 8; ++q) {
        float4 f = p[q];
        s += f.x * wls[q * 4 + 0] + f.y * wls[q * 4 + 1]
           + f.z * wls[q * 4 + 2] + f.w * wls[q * 4 + 3];
    }
    out[k] = s;
}

extern "C" void kernel_launch(void* const* d_in, const int* in_sizes, int n_in,
                              void* d_out, int out_size, void* d_ws, size_t ws_size,
                              hipStream_t stream)
{
    const float* x  = (const float*)d_in[0];   // [8,32,1,48,48]
    const float* w0 = (const float*)d_in[1];   // [256,65,3,3]
    const float* b0 = (const float*)d_in[2];   // [256]
    const float* w1 = (const float*)d_in[3];   // [128,96,3,3]
    const float* b1 = (const float*)d_in[4];   // [128]
    const float* wl = (const float*)d_in[5];   // [1,32]
    const float* bl = (const float*)d_in[6];   // [1]
    float* out = (float*)d_out;                // [73728]

    float* ws = (float*)d_ws;
    const long n0 = 8L * 64 * HWSZ;   // 1179648
    const long n1 = 8L * 32 * HWSZ;   // 589824
    float* h0a = ws; ws += n0;
    float* h0b = ws; ws += n0;
    float* c0  = ws; ws += n0;
    float* h1a = ws; ws += n1;
    float* h1b = ws; ws += n1;
    float* c1  = ws; ws += n1;
    float* seq = ws; ws += 32L * 32 * HWSZ;    // [T][32][2304] for batch 0

    // Zero initial states every call (deterministic; ws is not re-poisoned).
    hipMemsetAsync(h0a, 0, n0 * 4, stream);
    hipMemsetAsync(c0,  0, n0 * 4, stream);
    hipMemsetAsync(h1a, 0, n1 * 4, stream);
    hipMemsetAsync(c1,  0, n1 * 4, stream);

    float* h0c = h0a; float* h0n = h0b;
    float* h1c = h1a; float* h1n = h1b;
    for (int t = 0; t < TT; ++t) {
        // layer0: 65 in-ch = 5 chunks of 13; NOC=4 -> 16 groups; 1536 blocks
        convlstm_step<1, 64, 4, 13><<<dim3(12, 16, BB), dim3(48, 4), 0, stream>>>(
            x + (long)t * HWSZ, (long)TT * HWSZ, h0c, w0, b0, c0, h0n, nullptr);
        // layer1: 96 in-ch = 6 chunks of 16; NOC=2 -> 16 groups; 1536 blocks
        convlstm_step<64, 32, 2, 16><<<dim3(12, 16, BB), dim3(48, 4), 0, stream>>>(
            h0n, (long)64 * HWSZ, h1c, w1, b1, c1, h1n,
            seq + (long)t * 32 * HWSZ);
        float* tmp;
        tmp = h0c; h0c = h0n; h0n = tmp;
        tmp = h1c; h1c = h1n; h1n = tmp;
    }
    head_kernel<<<(73728 + 255) / 256, 256, 0, stream>>>(seq, wl, bl, out, 73728);
}

// Round 5
// 5143.150 us; speedup vs baseline: 5.6759x; 1.4809x over previous
//
#include <hip/hip_runtime.h>
#include <cmath>

#define HH 48
#define WW 48
#define HWSZ 2304
#define BB 8
#define TT 32

// One block-tile: 4 output rows x 48 cols, NOC hidden channels, one batch.
// 192 threads = 48 tx x 4 ty; hty = ty%NOC selects hidden channel,
// rb = (ty/NOC)*NOC selects row group; each thread owns RPT=NOC rows.
// LDS tile row stride TW=56 floats: x=0 lives at col 4 so interior float4
// writes are 16B-aligned; halo cols 3 (x=-1) and 52 (x=48) are always outside
// the image -> zeroed once at start. Weights packed [chi][h][tap][gate].
template<int CIN, int CHID, int NOC, int CHUNK>
__device__ __forceinline__ void convlstm_body(
    float* __restrict__ smem,
    int tileix, int ocg, int b,
    const float* __restrict__ xin, long xbstride,
    const float* __restrict__ hin,
    const float* __restrict__ w,
    const float* __restrict__ bias,
    float* __restrict__ cstate,
    float* __restrict__ hout,
    float* __restrict__ seq_t)
{
    constexpr int CTOT = CIN + CHID;
    static_assert(CTOT % CHUNK == 0, "");
    constexpr int NCHUNK = CTOT / CHUNK;
    constexpr int RPT = NOC;
    constexpr int TW = 56;

    float* tile = smem;                        // [CHUNK][6][TW]
    float* wlds = smem + CHUNK * 6 * TW;       // [CHUNK][NOC][9][4]

    const int tx  = threadIdx.x;        // 0..47
    const int ty  = threadIdx.y;        // 0..3
    const int tid = ty * 48 + tx;
    const int ty0 = tileix * 4;
    const int hc0 = ocg * NOC;
    const int hty = ty % NOC;
    const int rb  = (ty / NOC) * RPT;

    float acc[4][RPT];
    #pragma unroll
    for (int g = 0; g < 4; ++g)
        #pragma unroll
        for (int r = 0; r < RPT; ++r) acc[g][r] = 0.f;

    // Halo columns (x=-1 at col 3, x=48 at col 52) are always outside the
    // 48-wide image: zero once, reused by every chunk.
    for (int idx = tid; idx < CHUNK * 6 * 2; idx += 192) {
        int side = idx & 1;
        int rc = idx >> 1;                  // chi*6 + row
        tile[rc * TW + (side ? 52 : 3)] = 0.f;
    }

    const float* xb = xin + (long)b * xbstride;
    const float* hb = hin + (long)b * CHID * HWSZ;

    for (int chunk = 0; chunk < NCHUNK; ++chunk) {
        const int ic0 = chunk * CHUNK;
        __syncthreads();
        // Interior staging: CHUNK*6 rows x 12 float4 (aligned both sides).
        constexpr int NF4 = CHUNK * 6 * 12;
        for (int idx = tid; idx < NF4; idx += 192) {
            int f4 = idx % 12;
            int rc = idx / 12;
            int row = rc % 6;
            int chi = rc / 6;
            int gy = ty0 - 1 + row;
            int ic = ic0 + chi;
            const float* src = (ic < CIN) ? (xb + ic * HWSZ)
                                          : (hb + (ic - CIN) * HWSZ);
            float4 v = make_float4(0.f, 0.f, 0.f, 0.f);
            if (gy >= 0 && gy < HH)
                v = *(const float4*)(src + gy * WW + f4 * 4);
            *(float4*)(tile + (chi * 6 + row) * TW + 4 + f4 * 4) = v;
        }
        // Weight staging: linear idx == LDS write addr, layout [chi][h][k][g].
        constexpr int NWF = CHUNK * NOC * 36;
        for (int idx = tid; idx < NWF; idx += 192) {
            int g = idx & 3;
            int t2 = idx >> 2;
            int k = t2 % 9; t2 /= 9;
            int h = t2 % NOC;
            int chi = t2 / NOC;
            int ic = ic0 + chi;
            wlds[idx] = w[(((long)(g * CHID + hc0 + h)) * CTOT + ic) * 9 + k];
        }
        __syncthreads();

        const float* tbase = tile + rb * TW + 3 + tx;   // (row rb-1.., x=tx-1)
        const float* wbase = wlds + hty * 36;
        #pragma unroll
        for (int chi = 0; chi < CHUNK; ++chi) {
            // RPT+2 input rows x 3 cols; all offsets compile-time immediates.
            float vin[RPT + 2][3];
            #pragma unroll
            for (int rr = 0; rr < RPT + 2; ++rr)
                #pragma unroll
                for (int cc = 0; cc < 3; ++cc)
                    vin[rr][cc] = tbase[chi * 6 * TW + rr * TW + cc];

            const float4* wp = (const float4*)(wbase + chi * NOC * 36);
            #pragma unroll
            for (int k = 0; k < 9; ++k) {
                float4 wv = wp[k];          // {wi, wf, wo, wg} for tap k
                const int dy = k / 3, dx = k % 3;
                #pragma unroll
                for (int r = 0; r < RPT; ++r) {
                    float xv = vin[r + dy][dx];
                    acc[0][r] += xv * wv.x;
                    acc[1][r] += xv * wv.y;
                    acc[2][r] += xv * wv.z;
                    acc[3][r] += xv * wv.w;
                }
            }
        }
    }

    // LSTM pointwise update (gate order: i, f, o, g).
    const int c = hc0 + hty;
    const float bi  = bias[c];
    const float bff = bias[CHID + c];
    const float bo  = bias[2 * CHID + c];
    const float bg  = bias[3 * CHID + c];
    #pragma unroll
    for (int r = 0; r < RPT; ++r) {
        int y = ty0 + rb + r;
        long off = ((long)(b * CHID + c)) * HWSZ + y * WW + tx;
        float i_ = 1.f / (1.f + __expf(-(acc[0][r] + bi)));
        float f_ = 1.f / (1.f + __expf(-(acc[1][r] + bff)));
        float o_ = 1.f / (1.f + __expf(-(acc[2][r] + bo)));
        float g_ = tanhf(acc[3][r] + bg);
        float cp = cstate[off];
        float cn = f_ * cp + i_ * g_;
        float hn = o_ * tanhf(cn);
        cstate[off] = cn;
        hout[off] = hn;
        if (seq_t != nullptr && b == 0)
            seq_t[c * HWSZ + y * WW + tx] = hn;
    }
}

// smem sizes (floats)
#define SMEM_L0 (13 * 6 * 56 + 13 * 4 * 36)   // 6240
#define SMEM_L1 (16 * 6 * 56 + 16 * 2 * 36)   // 6528
#define SMEM_MAX 6528

template<int CIN, int CHID, int NOC, int CHUNK, int SMEMF>
__global__ __launch_bounds__(192, 5) void convlstm_step(
    const float* __restrict__ xin, long xbstride,
    const float* __restrict__ hin,
    const float* __restrict__ w,
    const float* __restrict__ bias,
    float* __restrict__ cstate,
    float* __restrict__ hout,
    float* __restrict__ seq_t)
{
    __shared__ __align__(16) float smem[SMEMF];
    convlstm_body<CIN, CHID, NOC, CHUNK>(smem, blockIdx.x, blockIdx.y,
                                         blockIdx.z, xin, xbstride, hin, w,
                                         bias, cstate, hout, seq_t);
}

// Fused launch: layer0 at step t (blockIdx.y 0..15) and layer1 at step t-1
// (blockIdx.y 16..31). Both depend only on h0prev (layer0's t-1 output).
__global__ __launch_bounds__(192, 5) void convlstm_fused(
    const float* __restrict__ x_t,
    const float* __restrict__ h0prev,
    const float* __restrict__ w0, const float* __restrict__ b0,
    float* __restrict__ c0, float* __restrict__ h0next,
    const float* __restrict__ w1, const float* __restrict__ b1,
    const float* __restrict__ h1prev,
    float* __restrict__ c1, float* __restrict__ h1next,
    float* __restrict__ seq_t)
{
    __shared__ __align__(16) float smem[SMEM_MAX];
    if (blockIdx.y < 16) {
        convlstm_body<1, 64, 4, 13>(smem, blockIdx.x, blockIdx.y, blockIdx.z,
                                    x_t, (long)TT * HWSZ, h0prev, w0, b0,
                                    c0, h0next, nullptr);
    } else {
        convlstm_body<64, 32, 2, 16>(smem, blockIdx.x, blockIdx.y - 16,
                                     blockIdx.z, h0prev, 64L * HWSZ, h1prev,
                                     w1, b1, c1, h1next, seq_t);
    }
}

// out[k] = bl + sum_j wl[j] * seq_flat[32k + j]
__global__ void head_kernel(const float* __restrict__ seq,
                            const float* __restrict__ wl,
                            const float* __restrict__ bl,
                            float* __restrict__ out, int n)
{
    __shared__ float wls[32];
    if (threadIdx.x < 32) wls[threadIdx.x] = wl[threadIdx.x];
    __syncthreads();
    int k = blockIdx.x * 256 + threadIdx.x;
    if (k >= n) return;
    const float4* p = (const float4*)(seq + (long)k * 32);
    float s = bl[0];
    #pragma unroll
    for (int q = 0; q < 8; ++q) {
        float4 f = p[q];
        s += f.x * wls[q * 4 + 0] + f.y * wls[q * 4 + 1]
           + f.z * wls[q * 4 + 2] + f.w * wls[q * 4 + 3];
    }
    out[k] = s;
}

extern "C" void kernel_launch(void* const* d_in, const int* in_sizes, int n_in,
                              void* d_out, int out_size, void* d_ws, size_t ws_size,
                              hipStream_t stream)
{
    const float* x  = (const float*)d_in[0];   // [8,32,1,48,48]
    const float* w0 = (const float*)d_in[1];   // [256,65,3,3]
    const float* b0 = (const float*)d_in[2];   // [256]
    const float* w1 = (const float*)d_in[3];   // [128,96,3,3]
    const float* b1 = (const float*)d_in[4];   // [128]
    const float* wl = (const float*)d_in[5];   // [1,32]
    const float* bl = (const float*)d_in[6];   // [1]
    float* out = (float*)d_out;                // [73728]

    float* ws = (float*)d_ws;
    const long n0 = 8L * 64 * HWSZ;   // 1179648
    const long n1 = 8L * 32 * HWSZ;   // 589824
    float* h0a = ws; ws += n0;
    float* h0b = ws; ws += n0;
    float* c0  = ws; ws += n0;
    float* h1a = ws; ws += n1;
    float* h1b = ws; ws += n1;
    float* c1  = ws; ws += n1;
    float* seq = ws; ws += 32L * 32 * HWSZ;    // [T][32][2304] for batch 0

    // Zero initial states every call (deterministic; ws is not re-poisoned).
    hipMemsetAsync(h0a, 0, n0 * 4, stream);
    hipMemsetAsync(c0,  0, n0 * 4, stream);
    hipMemsetAsync(h1a, 0, n1 * 4, stream);
    hipMemsetAsync(c1,  0, n1 * 4, stream);

    // t=0: layer0 only. in-state h0a (zeros) -> out h0b.
    convlstm_step<1, 64, 4, 13, SMEM_L0>
        <<<dim3(12, 16, BB), dim3(48, 4), 0, stream>>>(
            x, (long)TT * HWSZ, h0a, w0, b0, c0, h0b, nullptr);
    float* h0p = h0b;   // h0 output of step t-1
    float* h0n = h0a;
    float* h1p = h1a;   // h1 state (zeros initially)
    float* h1n = h1b;

    for (int t = 1; t < TT; ++t) {
        convlstm_fused<<<dim3(12, 32, BB), dim3(48, 4), 0, stream>>>(
            x + (long)t * HWSZ, h0p, w0, b0, c0, h0n,
            w1, b1, h1p, c1, h1n, seq + (long)(t - 1) * 32 * HWSZ);
        float* tmp;
        tmp = h0p; h0p = h0n; h0n = tmp;
        tmp = h1p; h1p = h1n; h1n = tmp;
    }
    // final: layer1 at t=31.
    convlstm_step<64, 32, 2, 16, SMEM_L1>
        <<<dim3(12, 16, BB), dim3(48, 4), 0, stream>>>(
            h0p, 64L * HWSZ, h1p, w1, b1, c1, h1n,
            seq + 31L * 32 * HWSZ);

    head_kernel<<<(73728 + 255) / 256, 256, 0, stream>>>(seq, wl, bl, out, 73728);
}

// Round 7
// 2646.070 us; speedup vs baseline: 11.0321x; 1.9437x over previous
//
#include <hip/hip_runtime.h>
#include <cmath>

#define HH 48
#define WW 48
#define HWSZ 2304
#define BB 8
#define TT 32

typedef __attribute__((ext_vector_type(8))) short bf16x8;
typedef __attribute__((ext_vector_type(16))) float f32x16;
typedef __attribute__((ext_vector_type(4))) float f32x4;

__device__ __forceinline__ unsigned short f2bf(float f) {
    unsigned int u = __float_as_uint(f);
    u = (u + 0x7fffu + ((u >> 16) & 1u)) >> 16;
    return (unsigned short)u;
}
__device__ __forceinline__ float bf2f(unsigned short s) {
    return __uint_as_float(((unsigned int)s) << 16);
}
__device__ __forceinline__ float sigm(float x) { return 1.f / (1.f + __expf(-x)); }

// ---------------- LDS layout (bytes) ----------------
// in-tile : [0, 41472)  unit u = (rc*2+pl)*4 + su ; rc = row*18+col (18x18 tile),
//           su = k16*2 + khalf ; byte = u*16 ^ ((col&7)<<4)
// W buf   : [41472, 57856)  unit = ((pl*4+g)*2+k16)*64 + hc*2 + kh ; byte ^= ((hc&7)<<4)
// bias    : [57856, 58880)
#define LDS_W 41472
#define LDS_BIAS 57856
#define LDS_TOTAL 58880

// Wfmt: per layer, [hcg][kb][tap][1024 units][8 bf16]; unit u:
//   kh=u&1, hc=(u>>1)&31, k16=(u>>6)&1, g=(u>>7)&3, pl=u>>9
//   element j -> ch_local = k16*16 + kh*8 + j
// Reference concatenates [x, h]: for layer0, w input-channel 0 is x and
// channels 1..64 are h. Our in-buffer holds h at positions 0..63 and x
// separately, so h block kb<2 maps to w-ic (kb*32+chl+1), x maps to w-ic 0.
template<int LAYER>
__global__ void wprep_kernel(const float* __restrict__ w, unsigned short* __restrict__ wf)
{
    constexpr int CHID = LAYER == 0 ? 64 : 32;
    constexpr int CTOT = LAYER == 0 ? 65 : 96;
    constexpr int NHCG = LAYER == 0 ? 2 : 1;
    const int gid = blockIdx.x * 256 + threadIdx.x;
    if (gid >= NHCG * 3 * 9 * 1024) return;
    const int u = gid & 1023;
    const int tapg = gid >> 10;
    const int tap = tapg % 9;
    const int kb = (tapg / 9) % 3;
    const int hcg = tapg / 27;
    const int kh = u & 1, hc = (u >> 1) & 31, k16 = (u >> 6) & 1, g = (u >> 7) & 3, pl = u >> 9;
    const int hcrow = hcg * 32 + hc;
    unsigned short vals[8] __attribute__((aligned(16)));
    #pragma unroll
    for (int j = 0; j < 8; ++j) {
        const int chl = k16 * 16 + kh * 8 + j;
        int ic;
        if (LAYER == 0) ic = (kb < 2) ? (kb * 32 + chl + 1) : (chl == 0 ? 0 : -1);
        else            ic = kb * 32 + chl;
        float v = 0.f;
        if (ic >= 0) v = w[((long)(g * CHID + hcrow) * CTOT + ic) * 9 + tap];
        const unsigned short hi = f2bf(v);
        vals[j] = pl ? f2bf(v - bf2f(hi)) : hi;
    }
    *(uint4*)(wf + (long)gid * 8) = *(const uint4*)vals;
}

// x split: xh/xl layout [t][b][pix]
__global__ void xprep_kernel(const float* __restrict__ x,
                             unsigned short* __restrict__ xh,
                             unsigned short* __restrict__ xl)
{
    const int gid = blockIdx.x * 256 + threadIdx.x;
    if (gid >= TT * BB * HWSZ) return;
    const int pix = gid % HWSZ;
    const int b = (gid / HWSZ) % BB;
    const int t = gid / (HWSZ * BB);
    const float v = x[((long)b * TT + t) * HWSZ + pix];
    const unsigned short hi = f2bf(v);
    xh[gid] = hi;
    xl[gid] = f2bf(v - bf2f(hi));
}

template<int LAYER>
__device__ void step_body(
    char* smem, int hcg, int pxst, int b, int slotrow,
    const unsigned short* __restrict__ in_hi,
    const unsigned short* __restrict__ in_lo,
    unsigned short* __restrict__ out_hi,
    unsigned short* __restrict__ out_lo,
    const unsigned short* __restrict__ xh_b,
    const unsigned short* __restrict__ xl_b,
    const unsigned short* __restrict__ wf,
    const float* __restrict__ bias,
    float* __restrict__ cbuf,
    float* __restrict__ seq_t)
{
    constexpr int CHID = LAYER == 0 ? 64 : 32;
    const int tid = threadIdx.x;
    const int lane = tid & 63;
    const int wid = tid >> 6;
    const int xbase = (pxst % 3) * 16;
    const int ybase = (pxst / 3) * 16;
    const int wyoff = wid * 4;
    const int n15 = lane & 15;
    const int nys = (lane >> 4) & 1;
    const int ksel = lane >> 5;
    const int hc7A = (lane & 7) << 4;

    f32x16 acc[4][2];
    #pragma unroll
    for (int g = 0; g < 4; ++g) {
        acc[g][0] = (f32x16)(0.f);
        acc[g][1] = (f32x16)(0.f);
    }

    if (tid < 4 * CHID) ((float*)(smem + LDS_BIAS))[tid] = bias[tid];

    const long pixbase = (long)b * HWSZ;

    for (int kbi = 0; kbi < 3; ++kbi) {
        const bool isx = (LAYER == 0) && (kbi == 2);
        const int nk16 = isx ? 1 : 2;
        const int choff = kbi * 32;

        // ---- stage in-tile (18 rows x 18 cols x 32ch x {hi,lo}) ----
        for (int u = tid; u < 2592; u += 256) {
            const int su = u & 3;
            const int pl = (u >> 2) & 1;
            const int rc = u >> 3;
            const int row = rc / 18, col = rc - row * 18;
            const int gy = ybase - 1 + row, gx = xbase - 1 + col;
            uint4 v = make_uint4(0u, 0u, 0u, 0u);
            if (gy >= 0 && gy < HH && gx >= 0 && gx < WW) {
                if (!isx) {
                    const unsigned short* src = pl ? in_lo : in_hi;
                    v = *(const uint4*)(src + (pixbase + gy * WW + gx) * 96 + choff + su * 8);
                } else if (su == 0) {
                    const unsigned short* xs = pl ? xl_b : xh_b;
                    v.x = (unsigned int)xs[gy * WW + gx];
                }
            }
            *(uint4*)(smem + ((u << 4) ^ ((col & 7) << 4))) = v;
        }
        // ---- stage W (tap 0) ----
        const unsigned short* wkb = wf + ((long)(hcg * 3 + kbi) * 9) * 8192;
        #pragma unroll
        for (int i = 0; i < 4; ++i) {
            const int u = tid + 256 * i;
            const uint4 v = *(const uint4*)(wkb + u * 8);
            *(uint4*)(smem + LDS_W + ((u << 4) ^ (((u >> 1) & 7) << 4))) = v;
        }
        __syncthreads();

        const int rcb = (wyoff + nys) * 18 + n15;
        for (int tap = 0; tap < 9; ++tap) {
            const int dy = tap / 3, dx = tap - dy * 3;
            uint4 wpre[4];
            if (tap < 8) {
                #pragma unroll
                for (int i = 0; i < 4; ++i)
                    wpre[i] = *(const uint4*)(wkb + (long)(tap + 1) * 8192 + (tid + 256 * i) * 8);
            }
            const int c7 = ((n15 + dx) & 7) << 4;
            for (int k16 = 0; k16 < nk16; ++k16) {
                bf16x8 Ah[4], Al[4];
                #pragma unroll
                for (int g = 0; g < 4; ++g) {
                    const int uh = (g * 2 + k16) * 64 + (lane & 31) * 2 + ksel;
                    const int ul = ((4 + g) * 2 + k16) * 64 + (lane & 31) * 2 + ksel;
                    Ah[g] = *(const bf16x8*)(smem + LDS_W + ((uh << 4) ^ hc7A));
                    Al[g] = *(const bf16x8*)(smem + LDS_W + ((ul << 4) ^ hc7A));
                }
                #pragma unroll
                for (int pxt = 0; pxt < 2; ++pxt) {
                    const int rc = rcb + (pxt * 2 + dy) * 18 + dx;
                    const int ub = rc * 8 + k16 * 2 + ksel;
                    const bf16x8 Bh = *(const bf16x8*)(smem + ((ub << 4) ^ c7));
                    const bf16x8 Bl = *(const bf16x8*)(smem + (((ub + 4) << 4) ^ c7));
                    #pragma unroll
                    for (int g = 0; g < 4; ++g) {
                        acc[g][pxt] = __builtin_amdgcn_mfma_f32_32x32x16_bf16(Al[g], Bh, acc[g][pxt], 0, 0, 0);
                        acc[g][pxt] = __builtin_amdgcn_mfma_f32_32x32x16_bf16(Ah[g], Bl, acc[g][pxt], 0, 0, 0);
                        acc[g][pxt] = __builtin_amdgcn_mfma_f32_32x32x16_bf16(Ah[g], Bh, acc[g][pxt], 0, 0, 0);
                    }
                }
            }
            __syncthreads();
            if (tap < 8) {
                #pragma unroll
                for (int i = 0; i < 4; ++i) {
                    const int u = tid + 256 * i;
                    *(uint4*)(smem + LDS_W + ((u << 4) ^ (((u >> 1) & 7) << 4))) = wpre[i];
                }
                __syncthreads();
            }
        }
    }

    // ---- epilogue: LSTM pointwise, D layout: n=lane&31, m=(r&3)+8*(r>>2)+4*(lane>>5) ----
    const float* bl = (const float*)(smem + LDS_BIAS);
    float* cslot = cbuf + ((long)(slotrow * 9 + pxst) * 4 + wid) * 2048;
    const int OUTCH = (LAYER == 0) ? hcg * 32 : 64;
    #pragma unroll
    for (int pxt = 0; pxt < 2; ++pxt) {
        const int ybl = wyoff + pxt * 2 + nys;
        const int pix = (ybase + ybl) * WW + xbase + n15;
        #pragma unroll
        for (int q = 0; q < 4; ++q) {
            f32x4 cp = *(const f32x4*)(cslot + ((pxt * 4 + q) * 64 + lane) * 4);
            f32x4 cn;
            short4 sh, sl4;
            #pragma unroll
            for (int e = 0; e < 4; ++e) {
                const int r = q * 4 + e;
                const int m = e + 8 * q + 4 * ksel;
                const int cch = hcg * 32 + m;
                const float i_ = sigm(acc[0][pxt][r] + bl[cch]);
                const float f_ = sigm(acc[1][pxt][r] + bl[CHID + cch]);
                const float o_ = sigm(acc[2][pxt][r] + bl[2 * CHID + cch]);
                const float g_ = tanhf(acc[3][pxt][r] + bl[3 * CHID + cch]);
                const float cv = f_ * cp[e] + i_ * g_;
                const float hv = o_ * tanhf(cv);
                cn[e] = cv;
                const unsigned short hi = f2bf(hv);
                ((unsigned short*)&sh)[e] = (short)hi;
                ((unsigned short*)&sl4)[e] = (short)f2bf(hv - bf2f(hi));
                if (LAYER == 1 && seq_t != nullptr)
                    seq_t[(long)m * HWSZ + pix] = hv;
            }
            *(f32x4*)(cslot + ((pxt * 4 + q) * 64 + lane) * 4) = cn;
            const long off = (pixbase + pix) * 96 + OUTCH + 8 * q + 4 * ksel;
            *(short4*)(out_hi + off) = sh;
            *(short4*)(out_lo + off) = sl4;
        }
    }
}

__global__ __launch_bounds__(256, 2) void fused_step(
    const unsigned short* __restrict__ in_hi, const unsigned short* __restrict__ in_lo,
    unsigned short* __restrict__ out_hi, unsigned short* __restrict__ out_lo,
    const unsigned short* __restrict__ xh_t, const unsigned short* __restrict__ xl_t,
    const unsigned short* __restrict__ wf0, const unsigned short* __restrict__ wf1,
    const float* __restrict__ b0, const float* __restrict__ b1,
    float* __restrict__ cbuf, float* __restrict__ seq_t,
    int doL0, int doL1)
{
    extern __shared__ char smem[];
    const int gy = blockIdx.y, pxst = blockIdx.x, b = blockIdx.z;
    if (gy < 2) {
        if (!doL0) return;
        step_body<0>(smem, gy, pxst, b, b * 3 + gy, in_hi, in_lo, out_hi, out_lo,
                     xh_t + (long)b * HWSZ, xl_t + (long)b * HWSZ,
                     wf0, b0, cbuf, nullptr);
    } else {
        if (!doL1) return;
        step_body<1>(smem, 0, pxst, b, b * 3 + 2, in_hi, in_lo, out_hi, out_lo,
                     nullptr, nullptr, wf1, b1, cbuf,
                     (b == 0) ? seq_t : nullptr);
    }
}

// out[k] = bl + sum_j wl[j] * seq_flat[32k + j]   (seq layout [t][32ch][2304pix])
__global__ void head_kernel(const float* __restrict__ seq,
                            const float* __restrict__ wl,
                            const float* __restrict__ bl,
                            float* __restrict__ out, int n)
{
    __shared__ float wls[32];
    if (threadIdx.x < 32) wls[threadIdx.x] = wl[threadIdx.x];
    __syncthreads();
    int k = blockIdx.x * 256 + threadIdx.x;
    if (k >= n) return;
    const float4* p = (const float4*)(seq + (long)k * 32);
    float s = bl[0];
    #pragma unroll
    for (int q = 0; q < 8; ++q) {
        float4 f = p[q];
        s += f.x * wls[q * 4 + 0] + f.y * wls[q * 4 + 1]
           + f.z * wls[q * 4 + 2] + f.w * wls[q * 4 + 3];
    }
    out[k] = s;
}

extern "C" void kernel_launch(void* const* d_in, const int* in_sizes, int n_in,
                              void* d_out, int out_size, void* d_ws, size_t ws_size,
                              hipStream_t stream)
{
    const float* x  = (const float*)d_in[0];   // [8,32,1,48,48]
    const float* w0 = (const float*)d_in[1];   // [256,65,3,3]
    const float* b0 = (const float*)d_in[2];   // [256]
    const float* w1 = (const float*)d_in[3];   // [128,96,3,3]
    const float* b1 = (const float*)d_in[4];   // [128]
    const float* wl = (const float*)d_in[5];   // [1,32]
    const float* bl = (const float*)d_in[6];   // [1]
    float* out = (float*)d_out;                // [73728]

    char* p = (char*)d_ws;
    auto alloc = [&](size_t bytes) -> char* {
        char* r = p; p += (bytes + 255) & ~(size_t)255; return r;
    };
    const size_t inplane = (size_t)BB * HWSZ * 96 * 2;            // 3.54 MB
    unsigned short* inA_hi = (unsigned short*)alloc(inplane);
    unsigned short* inA_lo = (unsigned short*)alloc(inplane);
    unsigned short* inB_hi = (unsigned short*)alloc(inplane);
    unsigned short* inB_lo = (unsigned short*)alloc(inplane);
    unsigned short* xh = (unsigned short*)alloc((size_t)TT * BB * HWSZ * 2);
    unsigned short* xl = (unsigned short*)alloc((size_t)TT * BB * HWSZ * 2);
    unsigned short* wf0 = (unsigned short*)alloc((size_t)2 * 3 * 9 * 1024 * 16);
    unsigned short* wf1 = (unsigned short*)alloc((size_t)1 * 3 * 9 * 1024 * 16);
    float* cbuf = (float*)alloc((size_t)8 * 3 * 9 * 4 * 2048 * 4);  // 7.08 MB
    float* seq  = (float*)alloc((size_t)TT * 32 * HWSZ * 4);        // 9.44 MB

    hipMemsetAsync(inA_hi, 0, inplane, stream);
    hipMemsetAsync(inA_lo, 0, inplane, stream);
    hipMemsetAsync(inB_hi, 0, inplane, stream);
    hipMemsetAsync(inB_lo, 0, inplane, stream);
    hipMemsetAsync(cbuf, 0, (size_t)8 * 3 * 9 * 4 * 2048 * 4, stream);

    wprep_kernel<0><<<216, 256, 0, stream>>>(w0, wf0);
    wprep_kernel<1><<<108, 256, 0, stream>>>(w1, wf1);
    xprep_kernel<<<2304, 256, 0, stream>>>(x, xh, xl);

    for (int s = 0; s <= TT; ++s) {
        const unsigned short* cih = (s & 1) ? inB_hi : inA_hi;
        const unsigned short* cil = (s & 1) ? inB_lo : inA_lo;
        unsigned short* noh = (s & 1) ? inA_hi : inB_hi;
        unsigned short* nol = (s & 1) ? inA_lo : inB_lo;
        const int ts = (s < TT) ? s : (TT - 1);
        const int tq = (s >= 1) ? (s - 1) : 0;
        fused_step<<<dim3(9, 3, BB), 256, LDS_TOTAL, stream>>>(
            cih, cil, noh, nol,
            xh + (long)ts * BB * HWSZ, xl + (long)ts * BB * HWSZ,
            wf0, wf1, b0, b1, cbuf,
            seq + (long)tq * 32 * HWSZ,
            s < TT ? 1 : 0, s >= 1 ? 1 : 0);
    }
    head_kernel<<<288, 256, 0, stream>>>(seq, wl, bl, out, 73728);
}

// Round 8
// 2250.656 us; speedup vs baseline: 12.9704x; 1.1757x over previous
//
#include <hip/hip_runtime.h>
#include <cmath>

#define HH 48
#define WW 48
#define HWSZ 2304
#define BB 8
#define TT 32
#define PADPX 2688   // 64 guard + 2560 main + 64 guard
#define POFF 64

typedef unsigned short u16;
typedef __attribute__((ext_vector_type(8))) short bf16x8;
typedef __attribute__((ext_vector_type(16))) float f32x16;
typedef __attribute__((ext_vector_type(4))) float f32x4;

__device__ __forceinline__ u16 f2bf(float f) {
    unsigned int u = __float_as_uint(f);
    u = (u + 0x7fffu + ((u >> 16) & 1u)) >> 16;
    return (u16)u;
}
__device__ __forceinline__ float bf2f(u16 s) {
    return __uint_as_float(((unsigned int)s) << 16);
}
__device__ __forceinline__ float sigm(float x) { return 1.f / (1.f + __expf(-x)); }

// ---------------- weight fragments ----------------
// wfall frag index space (1 frag = 64 lanes x 8ch = 1KB, lane: row=lane&31,
// k=(lane>>5)*8+j):
//   [0,576)    : L0-h  [hcg2][cs4][tap9][g4][pl2]   (w0 ic = cs*16+k+1)
//   [576,2880) : L0-x  [hcg2][tv16][tap9][g4][pl2]  (w0 ic = 0, only k==tv)
//   [2880,3312): L1    [cs6][tap9][g4][pl2]         (w1 ic = cs*16+k)
__global__ void wprep(const float* __restrict__ w0, const float* __restrict__ w1,
                      u16* __restrict__ wf)
{
    const int gid = blockIdx.x * 256 + threadIdx.x;
    if (gid >= 3312 * 64) return;
    const int lane = gid & 63;
    const int f = gid >> 6;
    const int row = lane & 31;
    const int khalf = lane >> 5;
    float v[8];
    int pl;
    if (f < 576) {
        pl = f & 1;
        const int g = (f >> 1) & 3;
        int r = f >> 3;
        const int tap = r % 9; r /= 9;
        const int cs = r & 3;
        const int hcg = r >> 2;
        const int hc = hcg * 32 + row;
        #pragma unroll
        for (int j = 0; j < 8; ++j) {
            const int ic = cs * 16 + khalf * 8 + j + 1;
            v[j] = w0[((size_t)(g * 64 + hc) * 65 + ic) * 9 + tap];
        }
    } else if (f < 2880) {
        const int f2 = f - 576;
        pl = f2 & 1;
        const int g = (f2 >> 1) & 3;
        int r = f2 >> 3;
        const int tap = r % 9; r /= 9;
        const int tv = r & 15;
        const int hcg = r >> 4;
        const int hc = hcg * 32 + row;
        const float wx = w0[((size_t)(g * 64 + hc) * 65 + 0) * 9 + tap];
        #pragma unroll
        for (int j = 0; j < 8; ++j)
            v[j] = (khalf * 8 + j == tv) ? wx : 0.f;
    } else {
        const int f3 = f - 2880;
        pl = f3 & 1;
        const int g = (f3 >> 1) & 3;
        int r = f3 >> 3;
        const int tap = r % 9; r /= 9;
        const int cs = r;
        #pragma unroll
        for (int j = 0; j < 8; ++j) {
            const int ic = cs * 16 + khalf * 8 + j;
            v[j] = w1[((size_t)(g * 32 + row) * 96 + ic) * 9 + tap];
        }
    }
    u16 o[8] __attribute__((aligned(16)));
    #pragma unroll
    for (int j = 0; j < 8; ++j) {
        const u16 hi = f2bf(v[j]);
        o[j] = pl ? (u16)f2bf(v[j] - bf2f(hi)) : hi;
    }
    *(uint4*)(wf + (size_t)gid * 8) = *(const uint4*)o;
}

// x packed: [b][tb=2][2688 px][16ch], ch = t&15; padded-linear px, zero guard.
__global__ void xprep(const float* __restrict__ x,
                      u16* __restrict__ xh, u16* __restrict__ xl)
{
    const int gid = blockIdx.x * 256 + threadIdx.x;
    if (gid >= TT * BB * HWSZ) return;
    const int pix = gid % HWSZ;
    const int b = (gid / HWSZ) % BB;
    const int t = gid / (HWSZ * BB);
    const float v = x[((size_t)b * TT + t) * HWSZ + pix];
    const int y = pix / 48, xx = pix - y * 48;
    const int p = (y + 1) * 50 + (xx + 1);
    const size_t idx = ((size_t)(b * 2 + (t >> 4)) * PADPX + POFF + p) * 16 + (t & 15);
    const u16 hi = f2bf(v);
    xh[idx] = hi;
    xl[idx] = f2bf(v - bf2f(hi));
}

// one step: L0(t) [blocks 0..159] and L1(t-1) [blocks 160..239], no LDS,
// no barriers; wave = 32px x 32hid x 4 gates, split-bf16 3-term MFMA.
__global__ __launch_bounds__(512, 2) void mstep(
    const u16* __restrict__ in_hi, const u16* __restrict__ in_lo,
    u16* __restrict__ out_hi, u16* __restrict__ out_lo,
    const u16* __restrict__ xpk_hi, const u16* __restrict__ xpk_lo,
    const u16* __restrict__ wfall,
    const float* __restrict__ b0, const float* __restrict__ b1,
    float* __restrict__ cbuf, float* __restrict__ seq_t,
    int t, int doL0, int doL1)
{
    const int tid = threadIdx.x;
    const int lane = tid & 63;
    const int wv = __builtin_amdgcn_readfirstlane(tid >> 6);
    const int n = lane & 31;
    const int ksel = lane >> 5;
    const int bid = blockIdx.x;

    const bool isL0 = bid < 160;
    int hcg, b, pg;
    if (isL0) {
        if (!doL0) return;
        hcg = bid & 1; b = (bid >> 1) & 7; pg = bid >> 4;
    } else {
        if (!doL1) return;
        const int r = bid - 160;
        hcg = 0; b = r & 7; pg = r >> 3;
    }
    const int frag = pg * 8 + wv;
    if (frag >= 77) return;           // last valid out px is p=2448
    const int p0 = frag * 32;

    const int bvoff = n * 32 + ksel * 16;   // B lane byte offset
    const int avoff = lane * 16;            // A lane byte offset

    // acc init = bias (D elem r of lane: m = (r&3) + 8*(r>>2) + 4*ksel)
    const float* bias = isL0 ? b0 : b1;
    const int CHID = isL0 ? 64 : 32;
    const int hc0 = hcg * 32;
    f32x16 acc[4];
    #pragma unroll
    for (int g = 0; g < 4; ++g)
        #pragma unroll
        for (int q = 0; q < 4; ++q) {
            const float4 bv = *(const float4*)(bias + g * CHID + hc0 + 8 * q + 4 * ksel);
            acc[g][q * 4 + 0] = bv.x; acc[g][q * 4 + 1] = bv.y;
            acc[g][q * 4 + 2] = bv.z; acc[g][q * 4 + 3] = bv.w;
        }

    auto conv16 = [&](const u16* bh, const u16* bl, const u16* af) {
        #pragma unroll
        for (int tap = 0; tap < 9; ++tap) {
            const int toff = (tap / 3 - 1) * 50 + (tap % 3) - 1;
            const bf16x8 Bh = *(const bf16x8*)((const char*)bh + (long)(p0 + toff) * 32 + bvoff);
            const bf16x8 Bl = *(const bf16x8*)((const char*)bl + (long)(p0 + toff) * 32 + bvoff);
            const char* ab = (const char*)af + tap * 8192 + avoff;
            #pragma unroll
            for (int g = 0; g < 4; ++g) {
                const bf16x8 Ah = *(const bf16x8*)(ab + (g * 2 + 0) * 1024);
                const bf16x8 Al = *(const bf16x8*)(ab + (g * 2 + 1) * 1024);
                acc[g] = __builtin_amdgcn_mfma_f32_32x32x16_bf16(Al, Bh, acc[g], 0, 0, 0);
                acc[g] = __builtin_amdgcn_mfma_f32_32x32x16_bf16(Ah, Bl, acc[g], 0, 0, 0);
                acc[g] = __builtin_amdgcn_mfma_f32_32x32x16_bf16(Ah, Bh, acc[g], 0, 0, 0);
            }
        }
    };

    if (isL0) {
        #pragma unroll 1
        for (int cs = 0; cs < 4; ++cs) {
            conv16(in_hi + ((size_t)(cs * 8 + b) * PADPX + POFF) * 16,
                   in_lo + ((size_t)(cs * 8 + b) * PADPX + POFF) * 16,
                   wfall + (size_t)(hcg * 288 + cs * 72) * 512);
        }
        conv16(xpk_hi + ((size_t)(b * 2 + (t >> 4)) * PADPX + POFF) * 16,
               xpk_lo + ((size_t)(b * 2 + (t >> 4)) * PADPX + POFF) * 16,
               wfall + (size_t)(576 + hcg * 1152 + (t & 15) * 72) * 512);
    } else {
        #pragma unroll 1
        for (int cs = 0; cs < 6; ++cs) {
            conv16(in_hi + ((size_t)(cs * 8 + b) * PADPX + POFF) * 16,
                   in_lo + ((size_t)(cs * 8 + b) * PADPX + POFF) * 16,
                   wfall + (size_t)(2880 + cs * 72) * 512);
        }
    }

    // ---- epilogue: LSTM pointwise; lane owns one px p0+n, 16 m-rows ----
    const int p = p0 + n;
    const int py = p / 50, pxx = p - py * 50;
    const bool valid = (py >= 1) && (py < 49) && (pxx >= 1) && (pxx < 49);
    const int pix = (py - 1) * 48 + (pxx - 1);
    const int slot = isL0 ? ((hcg * 8 + b) * 80 + frag) : (1280 + b * 80 + frag);
    float* cs_ = cbuf + (size_t)slot * 1024;
    const int ksbase = isL0 ? hcg * 2 : 4;
    const bool doseq = (!isL0) && (b == 0) && valid;

    #pragma unroll
    for (int q = 0; q < 4; ++q) {
        f32x4 cp = *(const f32x4*)(cs_ + (q * 64 + lane) * 4);
        f32x4 cn;
        short4 sh, sl;
        #pragma unroll
        for (int e = 0; e < 4; ++e) {
            const int r = q * 4 + e;
            const float i_ = sigm(acc[0][r]);
            const float f_ = sigm(acc[1][r]);
            const float o_ = sigm(acc[2][r]);
            const float g_ = tanhf(acc[3][r]);
            const float cv = f_ * cp[e] + i_ * g_;
            const float hv = o_ * tanhf(cv);
            cn[e] = cv;
            const u16 hi = f2bf(hv);
            ((u16*)&sh)[e] = (short)hi;
            ((u16*)&sl)[e] = (short)f2bf(hv - bf2f(hi));
            if (doseq) {
                const int m = e + 8 * q + 4 * ksel;
                seq_t[(size_t)m * HWSZ + pix] = hv;
            }
        }
        *(f32x4*)(cs_ + (q * 64 + lane) * 4) = cn;
        if (valid) {
            const int ksl = ksbase + (q >> 1);
            const int off16 = 8 * (q & 1) + 4 * ksel;
            const size_t ob = ((size_t)(ksl * 8 + b) * PADPX + POFF + p) * 16 + off16;
            *(short4*)(out_hi + ob) = sh;
            *(short4*)(out_lo + ob) = sl;
        }
    }
}

// out[k] = bl + sum_j wl[j] * seq_flat[32k+j]   (seq layout [t][32ch][2304px])
__global__ void head_kernel(const float* __restrict__ seq,
                            const float* __restrict__ wl,
                            const float* __restrict__ bl,
                            float* __restrict__ out, int nk)
{
    __shared__ float wls[32];
    if (threadIdx.x < 32) wls[threadIdx.x] = wl[threadIdx.x];
    __syncthreads();
    int k = blockIdx.x * 256 + threadIdx.x;
    if (k >= nk) return;
    const float4* p = (const float4*)(seq + (size_t)k * 32);
    float s = bl[0];
    #pragma unroll
    for (int q = 0; q < 8; ++q) {
        float4 f = p[q];
        s += f.x * wls[q * 4 + 0] + f.y * wls[q * 4 + 1]
           + f.z * wls[q * 4 + 2] + f.w * wls[q * 4 + 3];
    }
    out[k] = s;
}

extern "C" void kernel_launch(void* const* d_in, const int* in_sizes, int n_in,
                              void* d_out, int out_size, void* d_ws, size_t ws_size,
                              hipStream_t stream)
{
    const float* x  = (const float*)d_in[0];   // [8,32,1,48,48]
    const float* w0 = (const float*)d_in[1];   // [256,65,3,3]
    const float* b0 = (const float*)d_in[2];   // [256]
    const float* w1 = (const float*)d_in[3];   // [128,96,3,3]
    const float* b1 = (const float*)d_in[4];   // [128]
    const float* wl = (const float*)d_in[5];   // [1,32]
    const float* bl = (const float*)d_in[6];   // [1]
    float* out = (float*)d_out;                // [73728]

    char* p = (char*)d_ws;
    auto alloc = [&](size_t bytes) -> char* {
        char* r = p; p += (bytes + 255) & ~(size_t)255; return r;
    };
    const size_t inbytes = (size_t)6 * BB * PADPX * 16 * 2;   // 4.13 MB
    u16* inA_hi = (u16*)alloc(inbytes);
    u16* inA_lo = (u16*)alloc(inbytes);
    u16* inB_hi = (u16*)alloc(inbytes);
    u16* inB_lo = (u16*)alloc(inbytes);
    const size_t xbytes = (size_t)BB * 2 * PADPX * 16 * 2;    // 1.38 MB
    u16* xpk_hi = (u16*)alloc(xbytes);
    u16* xpk_lo = (u16*)alloc(xbytes);
    u16* wfall  = (u16*)alloc((size_t)3312 * 1024);           // 3.39 MB
    float* cbuf = (float*)alloc((size_t)1920 * 1024 * 4);     // 7.86 MB
    float* seq  = (float*)alloc((size_t)TT * 32 * HWSZ * 4);  // 9.44 MB

    hipMemsetAsync(inA_hi, 0, inbytes, stream);
    hipMemsetAsync(inA_lo, 0, inbytes, stream);
    hipMemsetAsync(inB_hi, 0, inbytes, stream);
    hipMemsetAsync(inB_lo, 0, inbytes, stream);
    hipMemsetAsync(xpk_hi, 0, xbytes, stream);
    hipMemsetAsync(xpk_lo, 0, xbytes, stream);
    hipMemsetAsync(cbuf, 0, (size_t)1920 * 1024 * 4, stream);

    wprep<<<(3312 * 64 + 255) / 256, 256, 0, stream>>>(w0, w1, wfall);
    xprep<<<(TT * BB * HWSZ + 255) / 256, 256, 0, stream>>>(x, xpk_hi, xpk_lo);

    for (int s = 0; s <= TT; ++s) {
        const u16* cih = (s & 1) ? inB_hi : inA_hi;
        const u16* cil = (s & 1) ? inB_lo : inA_lo;
        u16* noh = (s & 1) ? inA_hi : inB_hi;
        u16* nol = (s & 1) ? inA_lo : inB_lo;
        const int tq = (s >= 1) ? (s - 1) : 0;
        mstep<<<240, 512, 0, stream>>>(
            cih, cil, noh, nol, xpk_hi, xpk_lo, wfall, b0, b1,
            cbuf, seq + (size_t)tq * 32 * HWSZ,
            (s < TT) ? s : 0, (s < TT) ? 1 : 0, (s >= 1) ? 1 : 0);
    }
    head_kernel<<<288, 256, 0, stream>>>(seq, wl, bl, out, 73728);
}